// Round 9
// baseline (242.054 us; speedup 1.0000x reference)
//
#include <hip/hip_runtime.h>

typedef _Float16 half8 __attribute__((ext_vector_type(8)));
typedef _Float16 half4v __attribute__((ext_vector_type(4)));
typedef float f32x4 __attribute__((ext_vector_type(4)));
typedef unsigned int u32;

#define SEQ 2048
#define NTOK 4096
#define DM 1024
#define QKS 2048
#define LN_EPS 1e-5f
#define LOG2E_SCALE 0.18033688f  // 0.125 * log2(e)

// ---------------- async global->LDS (16B per lane) ----------------
typedef const __attribute__((address_space(1))) u32* gas_ptr;
typedef __attribute__((address_space(3))) u32* las_ptr;
__device__ __forceinline__ void gld_lds16(const void* g, void* l) {
  __builtin_amdgcn_global_load_lds((gas_ptr)g, (las_ptr)l, 16, 0, 0);
}

#define BARRIER() do { __builtin_amdgcn_s_barrier(); __builtin_amdgcn_sched_barrier(0); } while (0)
#define VMW(N) do { asm volatile("s_waitcnt vmcnt(" #N ")" ::: "memory"); __builtin_amdgcn_sched_barrier(0); } while (0)
#define LGW() do { asm volatile("s_waitcnt lgkmcnt(0)" ::: "memory"); __builtin_amdgcn_sched_barrier(0); } while (0)

// ---------------- fused prepass: LN+cast, y cast, 4 weight transposes ----------------
__global__ __launch_bounds__(256) void prep_kernel(
    const float* __restrict__ x, const float* __restrict__ g, const float* __restrict__ bta,
    const float* __restrict__ y,
    const float* __restrict__ w_qkv, const float* __restrict__ w_av,
    const float* __restrict__ w_out, const float* __restrict__ w_yout,
    _Float16* __restrict__ xn, _Float16* __restrict__ yh,
    _Float16* __restrict__ wqkvT, _Float16* __restrict__ wavT,
    _Float16* __restrict__ woutT, _Float16* __restrict__ wyoutT) {
  __shared__ float smem[64 * 65];
  const int bid = blockIdx.x;
  const int t = threadIdx.x;
  if (bid < 4096) {  // LayerNorm row
    const int row = bid;
    const float4 v = ((const float4*)(x + (size_t)row * DM))[t];
    float s = v.x + v.y + v.z + v.w;
#pragma unroll
    for (int m = 1; m < 64; m <<= 1) s += __shfl_xor(s, m, 64);
    float* red = smem;
    const int wid = t >> 6, lane = t & 63;
    if (lane == 0) red[wid] = s;
    __syncthreads();
    const float mu = (red[0] + red[1] + red[2] + red[3]) * (1.0f / DM);
    const float dx = v.x - mu, dy = v.y - mu, dz = v.z - mu, dw = v.w - mu;
    float ss = dx * dx + dy * dy + dz * dz + dw * dw;
#pragma unroll
    for (int m = 1; m < 64; m <<= 1) ss += __shfl_xor(ss, m, 64);
    __syncthreads();
    if (lane == 0) red[wid] = ss;
    __syncthreads();
    const float var = (red[0] + red[1] + red[2] + red[3]) * (1.0f / DM);
    const float rstd = rsqrtf(var + LN_EPS);
    const float4 gg = ((const float4*)g)[t];
    const float4 bb = ((const float4*)bta)[t];
    half4v o;
    o[0] = (_Float16)(dx * rstd * gg.x + bb.x);
    o[1] = (_Float16)(dy * rstd * gg.y + bb.y);
    o[2] = (_Float16)(dz * rstd * gg.z + bb.z);
    o[3] = (_Float16)(dw * rstd * gg.w + bb.w);
    *(half4v*)(xn + (size_t)row * DM + t * 4) = o;
  } else if (bid < 8192) {  // y cast row
    const int row = bid - 4096;
    const float4 v = ((const float4*)(y + (size_t)row * DM))[t];
    half4v o;
    o[0] = (_Float16)v.x; o[1] = (_Float16)v.y;
    o[2] = (_Float16)v.z; o[3] = (_Float16)v.w;
    *(half4v*)(yh + (size_t)row * DM + t * 4) = o;
  } else {  // weight transpose+cast: W[K][Nc] -> WT[Nc][K]
    const int id2 = bid - 8192;
    const float* W; _Float16* WT; int Nc, bx, by;
    if (id2 < 768) { W = w_qkv; WT = wqkvT; Nc = 3072; bx = id2 % 48; by = id2 / 48; }
    else {
      const int id3 = id2 - 768, sel = id3 >> 8;
      Nc = 1024; bx = id3 & 15; by = (id3 >> 4) & 15;
      if (sel == 0) { W = w_av; WT = wavT; }
      else if (sel == 1) { W = w_out; WT = woutT; }
      else { W = w_yout; WT = wyoutT; }
    }
    float (*tile)[65] = (float(*)[65])smem;
    const int n0 = bx * 64, k0 = by * 64;
    const int c = t & 63;
#pragma unroll
    for (int i = 0; i < 16; i++) {
      const int r = (t >> 6) * 16 + i;
      tile[r][c] = W[(size_t)(k0 + r) * Nc + n0 + c];
    }
    __syncthreads();
#pragma unroll
    for (int i = 0; i < 16; i++) {
      const int n = (t >> 6) * 16 + i;
      WT[(size_t)(n0 + n) * 1024 + k0 + c] = (_Float16)tile[c][n];
    }
  }
}

// ---------------- 8-phase 256x256 GEMM (qkv + av fused), BK=32 dbuf ----------------
__global__ __launch_bounds__(512, 2) void gemm8p_kernel(
    const _Float16* __restrict__ xn, const _Float16* __restrict__ wqkvT,
    const _Float16* __restrict__ yh, const _Float16* __restrict__ wavT,
    _Float16* __restrict__ qkvm, _Float16* __restrict__ vtb,
    _Float16* __restrict__ avtb) {
  __shared__ _Float16 Ab[2][8192];
  __shared__ _Float16 Bb[2][8192];
  const int swz = ((blockIdx.x & 7) << 5) + (blockIdx.x >> 3);  // bijective, 256 blocks
  const _Float16 *A, *B;
  int m0, n0, isav;
  if (swz < 192) { A = xn; B = wqkvT; m0 = (swz / 12) * 256; n0 = (swz % 12) * 256; isav = 0; }
  else { const int u = swz - 192; A = yh; B = wavT; m0 = (u >> 2) * 256; n0 = (u & 3) * 256; isav = 1; }
  const int t = threadIdx.x;
  const int wid = t >> 6, lane = t & 63, lo = lane & 15, hi = lane >> 4;
  const int wm = wid >> 2, wn = wid & 3;
  const int srow = t >> 2;
  const int sx = ((t & 3) ^ (srow & 3)) << 3;  // swizzled 16B-chunk in source row
  const _Float16* gA = A + (size_t)(m0 + srow) * 1024 + sx;
  const _Float16* gB = B + (size_t)(n0 + srow) * 1024 + sx;
  const int rdz = (hi ^ (lo & 3)) << 3;
  const int arow = (wm * 128 + lo) * 32 + rdz;  // + f*512
  const int brow = (wn * 64 + lo) * 32 + rdz;   // + g*512

  f32x4 acc[8][4];
#pragma unroll
  for (int i = 0; i < 8; i++)
#pragma unroll
    for (int j = 0; j < 4; j++) {
      acc[i][j][0] = 0.f; acc[i][j][1] = 0.f; acc[i][j][2] = 0.f; acc[i][j][3] = 0.f;
    }
  half8 af[4], bf[4];

#define STG_A(BUF, HH, KT) gld_lds16(gA + (HH) * 131072 + (KT) * 32, &Ab[BUF][(HH) * 4096 + t * 8])
#define STG_B(BUF, HH, KT) gld_lds16(gB + (HH) * 131072 + (KT) * 32, &Bb[BUF][(HH) * 4096 + t * 8])
#define RDA(BUF, FB)                                                     \
  _Pragma("unroll") for (int f2 = 0; f2 < 4; f2++)                       \
      af[f2] = *(const half8*)&Ab[BUF][arow + ((FB) + f2) * 512]
#define RDB(BUF, G0)                                                     \
  _Pragma("unroll") for (int g2 = 0; g2 < 2; g2++)                       \
      bf[(G0) + g2] = *(const half8*)&Bb[BUF][brow + ((G0) + g2) * 512]
#define MMA(FB, G0)                                                      \
  do {                                                                   \
    __builtin_amdgcn_s_setprio(1);                                       \
    _Pragma("unroll") for (int f2 = 0; f2 < 4; f2++)                     \
        _Pragma("unroll") for (int g2 = 0; g2 < 2; g2++)                 \
            acc[(FB) + f2][(G0) + g2] = __builtin_amdgcn_mfma_f32_16x16x32_f16( \
                af[f2], bf[(G0) + g2], acc[(FB) + f2][(G0) + g2], 0, 0, 0); \
    __builtin_amdgcn_s_setprio(0);                                       \
  } while (0)

  // prologue: tile0 -> buf0 (4 halves), tile1 A-h0 -> buf1
  STG_A(0, 0, 0); STG_A(0, 1, 0); STG_B(0, 0, 0); STG_B(0, 1, 0);
  STG_A(1, 0, 1);

  for (int it = 0; it < 16; it++) {
    const int T1 = 2 * it + 1;
    const int N0 = (2 * it + 2) & 31, N1 = (2 * it + 3) & 31;
    // P0: open buf0
    VMW(1); BARRIER();
    RDA(0, 0); RDB(0, 0);
    STG_A(1, 1, T1);
    LGW(); MMA(0, 0);
    // P1
    BARRIER(); RDB(0, 2); STG_B(1, 0, T1); LGW(); MMA(0, 2);
    // P2
    BARRIER(); RDA(0, 4); STG_B(1, 1, T1); LGW(); MMA(4, 2);
    // P3
    BARRIER(); STG_A(0, 0, N0); MMA(4, 0);
    // P4: open buf1
    VMW(1); BARRIER();
    RDA(1, 0); RDB(1, 0);
    STG_A(0, 1, N0);
    LGW(); MMA(0, 0);
    // P5
    BARRIER(); RDB(1, 2); STG_B(0, 0, N0); LGW(); MMA(0, 2);
    // P6
    BARRIER(); RDA(1, 4); STG_B(0, 1, N0); LGW(); MMA(4, 2);
    // P7
    BARRIER(); STG_A(1, 0, N1); MMA(4, 0);
  }
#undef STG_A
#undef STG_B
#undef RDA
#undef RDB
#undef MMA

  // epilogue
#pragma unroll
  for (int f = 0; f < 8; f++)
#pragma unroll
    for (int g = 0; g < 4; g++)
#pragma unroll
      for (int r = 0; r < 4; r++) {
        const int row = m0 + wm * 128 + f * 16 + 4 * hi + r;
        const int col = n0 + wn * 64 + g * 16 + lo;
        const _Float16 v = (_Float16)acc[f][g][r];
        if (!isav && col < 2048) {
          qkvm[(size_t)row * QKS + col] = v;
        } else {
          const int coff = isav ? col : col - 2048;
          _Float16* Ct = isav ? avtb : vtb;
          Ct[(((size_t)((row >> 11) << 4) + (coff >> 6)) * 64 + (coff & 63)) * SEQ +
             (row & (SEQ - 1))] = v;
        }
      }
}

// ---------------- 8-phase 256x256 GEMM for output projections (f32 + bias) ----------------
__global__ __launch_bounds__(512, 2) void gemmout8p_kernel(
    const _Float16* __restrict__ xc, const _Float16* __restrict__ woutT,
    float* __restrict__ o0, const float* __restrict__ b0,
    const _Float16* __restrict__ yc, const _Float16* __restrict__ wyoutT,
    float* __restrict__ o1, const float* __restrict__ b1) {
  __shared__ _Float16 Ab[2][8192];
  __shared__ _Float16 Bb[2][8192];
  const int swz = ((blockIdx.x & 7) << 4) + (blockIdx.x >> 3);  // bijective, 128 blocks
  const _Float16 *A, *B;
  float* F; const float* bias;
  int u;
  if (swz < 64) { A = xc; B = woutT; F = o0; bias = b0; u = swz; }
  else { A = yc; B = wyoutT; F = o1; bias = b1; u = swz - 64; }
  const int m0 = (u >> 2) * 256, n0 = (u & 3) * 256;
  const int t = threadIdx.x;
  const int wid = t >> 6, lane = t & 63, lo = lane & 15, hi = lane >> 4;
  const int wm = wid >> 2, wn = wid & 3;
  const int srow = t >> 2;
  const int sx = ((t & 3) ^ (srow & 3)) << 3;
  const _Float16* gA = A + (size_t)(m0 + srow) * 1024 + sx;
  const _Float16* gB = B + (size_t)(n0 + srow) * 1024 + sx;
  const int rdz = (hi ^ (lo & 3)) << 3;
  const int arow = (wm * 128 + lo) * 32 + rdz;
  const int brow = (wn * 64 + lo) * 32 + rdz;

  f32x4 acc[8][4];
#pragma unroll
  for (int i = 0; i < 8; i++)
#pragma unroll
    for (int j = 0; j < 4; j++) {
      acc[i][j][0] = 0.f; acc[i][j][1] = 0.f; acc[i][j][2] = 0.f; acc[i][j][3] = 0.f;
    }
  half8 af[4], bf[4];

#define STG_A(BUF, HH, KT) gld_lds16(gA + (HH) * 131072 + (KT) * 32, &Ab[BUF][(HH) * 4096 + t * 8])
#define STG_B(BUF, HH, KT) gld_lds16(gB + (HH) * 131072 + (KT) * 32, &Bb[BUF][(HH) * 4096 + t * 8])
#define RDA(BUF, FB)                                                     \
  _Pragma("unroll") for (int f2 = 0; f2 < 4; f2++)                       \
      af[f2] = *(const half8*)&Ab[BUF][arow + ((FB) + f2) * 512]
#define RDB(BUF, G0)                                                     \
  _Pragma("unroll") for (int g2 = 0; g2 < 2; g2++)                       \
      bf[(G0) + g2] = *(const half8*)&Bb[BUF][brow + ((G0) + g2) * 512]
#define MMA(FB, G0)                                                      \
  do {                                                                   \
    __builtin_amdgcn_s_setprio(1);                                       \
    _Pragma("unroll") for (int f2 = 0; f2 < 4; f2++)                     \
        _Pragma("unroll") for (int g2 = 0; g2 < 2; g2++)                 \
            acc[(FB) + f2][(G0) + g2] = __builtin_amdgcn_mfma_f32_16x16x32_f16( \
                af[f2], bf[(G0) + g2], acc[(FB) + f2][(G0) + g2], 0, 0, 0); \
    __builtin_amdgcn_s_setprio(0);                                       \
  } while (0)

  STG_A(0, 0, 0); STG_A(0, 1, 0); STG_B(0, 0, 0); STG_B(0, 1, 0);
  STG_A(1, 0, 1);

  for (int it = 0; it < 16; it++) {
    const int T1 = 2 * it + 1;
    const int N0 = (2 * it + 2) & 31, N1 = (2 * it + 3) & 31;
    VMW(1); BARRIER();
    RDA(0, 0); RDB(0, 0);
    STG_A(1, 1, T1);
    LGW(); MMA(0, 0);
    BARRIER(); RDB(0, 2); STG_B(1, 0, T1); LGW(); MMA(0, 2);
    BARRIER(); RDA(0, 4); STG_B(1, 1, T1); LGW(); MMA(4, 2);
    BARRIER(); STG_A(0, 0, N0); MMA(4, 0);
    VMW(1); BARRIER();
    RDA(1, 0); RDB(1, 0);
    STG_A(0, 1, N0);
    LGW(); MMA(0, 0);
    BARRIER(); RDB(1, 2); STG_B(0, 0, N0); LGW(); MMA(0, 2);
    BARRIER(); RDA(1, 4); STG_B(0, 1, N0); LGW(); MMA(4, 2);
    BARRIER(); STG_A(1, 0, N1); MMA(4, 0);
  }
#undef STG_A
#undef STG_B
#undef RDA
#undef RDB
#undef MMA

#pragma unroll
  for (int f = 0; f < 8; f++)
#pragma unroll
    for (int g = 0; g < 4; g++)
#pragma unroll
      for (int r = 0; r < 4; r++) {
        const int row = m0 + wm * 128 + f * 16 + 4 * hi + r;
        const int col = n0 + wn * 64 + g * 16 + lo;
        F[(size_t)row * 1024 + col] = acc[f][g][r] + bias[col];
      }
}

// ---------------- flash attention v5: R3 body + 48KB LDS + T14 reg-staged V/AV ----------------
// K gld_lds dbuf (stage at tile top, 1-ahead). V/AV: global->regs issued END of
// previous tile (full-tile distance), regs->LDS after post-PV barrier.
// Steady-state vmcnt: top VMW(4) retires K(t); post-PV VMW(2) retires VA(t+1).
__global__ __launch_bounds__(256) void attn_kernel(
    const _Float16* __restrict__ qkvm,  // [NTOK][2048]: q | k
    const _Float16* __restrict__ vt,    // [32][64][SEQ]
    const _Float16* __restrict__ avt,   // [32][64][SEQ]
    _Float16* __restrict__ xctx, _Float16* __restrict__ yctx) {
  __shared__ _Float16 Kl[2][4096];
  __shared__ _Float16 Vl[4096];
  __shared__ _Float16 Al[4096];
  __shared__ _Float16 Pl[4][2048];

  const int t = threadIdx.x;
  const int wid = t >> 6, lane = t & 63, lo = lane & 15, hi = lane >> 4;
  const int l7 = lane & 7;
  const int id = blockIdx.x;
  const int bh = ((id & 7) << 2) + ((id >> 3) >> 4);
  const int qt = (id >> 3) & 15;
  const int b = bh >> 4, h = bh & 15;
  const int q0 = qt * 128 + wid * 32;
  const size_t tokbase = (size_t)b * SEQ;
  const _Float16* vbase = vt + (size_t)bh * 64 * SEQ;
  const _Float16* abase = avt + (size_t)bh * 64 * SEQ;
  _Float16* Pw = Pl[wid];
  const int NT = SEQ / 64;

  // Q as B-fragment: lane holds Q[q0+rg*16+lo][kc*32 + hi*8 .. +7]
  half8 qf[2][2];
#pragma unroll
  for (int rg = 0; rg < 2; rg++)
#pragma unroll
    for (int kc = 0; kc < 2; kc++)
      qf[rg][kc] = *(const half8*)(qkvm + (tokbase + q0 + rg * 16 + lo) * QKS +
                                   h * 64 + kc * 32 + hi * 8);

  f32x4 zero;
  zero[0] = 0.f; zero[1] = 0.f; zero[2] = 0.f; zero[3] = 0.f;
  f32x4 accx[2][4], accy[2][4];
  float mC[2], lsum[2];
#pragma unroll
  for (int rg = 0; rg < 2; rg++) {
#pragma unroll
    for (int j = 0; j < 4; j++) { accx[rg][j] = zero; accy[rg][j] = zero; }
    mC[rg] = -1.0e30f; lsum[rg] = 0.0f;
  }

  const int skey = t >> 3;  // K key-row / VA d-row
  const int sc7 = t & 7;

#define STAGE_K(kv0, BSEL)                                                        \
  do {                                                                            \
    _Pragma("unroll") for (int j = 0; j < 2; j++) {                               \
      const int key = skey + j * 32;                                              \
      const int cs = ((sc7 ^ (key & 7)) << 3);                                    \
      gld_lds16(qkvm + (tokbase + (kv0) + key) * QKS + DM + h * 64 + cs,          \
                &Kl[BSEL][j * 2048 + wid * 512]);                                 \
    }                                                                             \
  } while (0)

  half8 vreg[2], areg[2];
#define LOAD_VA(kv0)                                                              \
  do {                                                                            \
    _Pragma("unroll") for (int j = 0; j < 2; j++) {                               \
      const int drow = skey + j * 32;                                             \
      const int cs = ((sc7 ^ (drow & 7)) << 3);                                   \
      vreg[j] = *(const half8*)(vbase + (size_t)drow * SEQ + (kv0) + cs);         \
      areg[j] = *(const half8*)(abase + (size_t)drow * SEQ + (kv0) + cs);         \
    }                                                                             \
  } while (0)

#define WRITE_VA()                                                                \
  do {                                                                            \
    _Pragma("unroll") for (int j = 0; j < 2; j++) {                               \
      *(half8*)(Vl + j * 2048 + t * 8) = vreg[j];                                 \
      *(half8*)(Al + j * 2048 + t * 8) = areg[j];                                 \
    }                                                                             \
  } while (0)

  // prologue: K(0)+VA(0) via gld_lds [6 loads], then VA(1) -> regs [4 loads]
  STAGE_K(0, 0);
#pragma unroll
  for (int j = 0; j < 2; j++) {
    const int drow = skey + j * 32;
    const int cs = ((sc7 ^ (drow & 7)) << 3);
    gld_lds16(vbase + (size_t)drow * SEQ + cs, &Vl[j * 2048 + wid * 512]);
    gld_lds16(abase + (size_t)drow * SEQ + cs, &Al[j * 2048 + wid * 512]);
  }
  LOAD_VA(64);

  for (int tt = 0; tt < NT; tt++) {
    // top: K(t) and VA(t)-in-LDS must be ready; VA(t+1) regs stay in flight
    if (tt + 1 < NT) { VMW(4); } else { VMW(0); }
    BARRIER();
    if (tt + 1 < NT) STAGE_K((tt + 1) * 64, (tt & 1) ^ 1);
    const _Float16* Kb = Kl[tt & 1];

    // ---- S^T = K Q^T : s[rg][kg], row(key)=4*hi+r, col(query)=lo ----
    f32x4 s[2][4];
#pragma unroll
    for (int kg = 0; kg < 4; kg++) {
      const int kr = (kg * 16 + lo) * 64;
      const half8 ak0 = *(const half8*)(Kb + kr + ((hi ^ l7) << 3));
      const half8 ak1 = *(const half8*)(Kb + kr + (((4 | hi) ^ l7) << 3));
#pragma unroll
      for (int rg = 0; rg < 2; rg++) {
        f32x4 z = __builtin_amdgcn_mfma_f32_16x16x32_f16(ak0, qf[rg][0], zero, 0, 0, 0);
        s[rg][kg] = __builtin_amdgcn_mfma_f32_16x16x32_f16(ak1, qf[rg][1], z, 0, 0, 0);
      }
    }

    // ---- in-lane tile max + 2-step cross-lane ----
    float tmC[2];
#pragma unroll
    for (int rg = 0; rg < 2; rg++) {
      float tm = -3.0e38f;
#pragma unroll
      for (int kg = 0; kg < 4; kg++)
#pragma unroll
        for (int r = 0; r < 4; r++) tm = fmaxf(tm, s[rg][kg][r]);
      tm = fmaxf(tm, __shfl_xor(tm, 16, 64));
      tm = fmaxf(tm, __shfl_xor(tm, 32, 64));
      tmC[rg] = tm * LOG2E_SCALE;
    }

    // ---- defer-max rescale ----
    const bool grow = (tmC[0] > mC[0] + 8.0f) | (tmC[1] > mC[1] + 8.0f);
    if (__any(grow)) {
      float fcs[2];
#pragma unroll
      for (int rg = 0; rg < 2; rg++) {
        const float mn = fmaxf(mC[rg], tmC[rg]);
        fcs[rg] = exp2f(mC[rg] - mn);
        mC[rg] = mn;
        lsum[rg] *= fcs[rg];
      }
#pragma unroll
      for (int rg = 0; rg < 2; rg++)
#pragma unroll
        for (int r = 0; r < 4; r++) {
          const float fcb = __shfl(fcs[rg], 4 * hi + r, 64);
#pragma unroll
          for (int ng = 0; ng < 4; ng++) {
            accx[rg][ng][r] *= fcb;
            accy[rg][ng][r] *= fcb;
          }
        }
    }

    // ---- P = exp2(s*C - mC), in-lane sum, packed b64 write ----
#pragma unroll
    for (int rg = 0; rg < 2; rg++) {
      float rs = 0.0f;
#pragma unroll
      for (int kg = 0; kg < 4; kg++) {
        half4v pk;
#pragma unroll
        for (int r = 0; r < 4; r++) {
          const float p = exp2f(fmaf(s[rg][kg][r], LOG2E_SCALE, -mC[rg]));
          rs += p;
          pk[r] = (_Float16)p;
        }
        *(half4v*)(Pw + (rg * 16 + lo) * 64 +
                   (((kg * 2 + (hi >> 1)) ^ l7) << 3) + ((hi & 1) << 2)) = pk;
      }
      rs += __shfl_xor(rs, 16, 64);
      rs += __shfl_xor(rs, 32, 64);
      lsum[rg] += rs;
    }

    // ---- PV for both value streams ----
#pragma unroll
    for (int kk = 0; kk < 2; kk++) {
      half8 pa[2];
#pragma unroll
      for (int rg = 0; rg < 2; rg++)
        pa[rg] = *(const half8*)(Pw + (rg * 16 + lo) * 64 + (((kk * 4 + hi) ^ l7) << 3));
#pragma unroll
      for (int ng = 0; ng < 4; ng++) {
        const int vr = (ng * 16 + lo) * 64 + (((kk * 4 + hi) ^ l7) << 3);
        const half8 bv = *(const half8*)(Vl + vr);
        const half8 ba = *(const half8*)(Al + vr);
#pragma unroll
        for (int rg = 0; rg < 2; rg++) {
          accx[rg][ng] = __builtin_amdgcn_mfma_f32_16x16x32_f16(pa[rg], bv, accx[rg][ng], 0, 0, 0);
          accy[rg][ng] = __builtin_amdgcn_mfma_f32_16x16x32_f16(pa[rg], ba, accy[rg][ng], 0, 0, 0);
        }
      }
    }

    // ---- tail: retire VA(t+1) regs, post-PV barrier, write to LDS, issue VA(t+2) ----
    if (tt + 1 < NT) {
      VMW(2);
      BARRIER();
      WRITE_VA();
      LGW();
      if (tt + 2 < NT) LOAD_VA((tt + 2) * 64);
    }
  }
#undef STAGE_K
#undef LOAD_VA
#undef WRITE_VA

  // ---- normalize and store ----
#pragma unroll
  for (int rg = 0; rg < 2; rg++) {
    const float inv = 1.0f / lsum[rg];
#pragma unroll
    for (int r = 0; r < 4; r++) {
      const float invb = __shfl(inv, 4 * hi + r, 64);
      const size_t tok = tokbase + q0 + rg * 16 + 4 * hi + r;
#pragma unroll
      for (int ng = 0; ng < 4; ng++) {
        const int col = h * 64 + ng * 16 + lo;
        xctx[tok * DM + col] = (_Float16)(accx[rg][ng][r] * invb);
        yctx[tok * DM + col] = (_Float16)(accy[rg][ng][r] * invb);
      }
    }
  }
}

// ---------------- launch ----------------
extern "C" void kernel_launch(void* const* d_in, const int* in_sizes, int n_in,
                              void* d_out, int out_size, void* d_ws, size_t ws_size,
                              hipStream_t stream) {
  const float* x      = (const float*)d_in[0];
  const float* y      = (const float*)d_in[1];
  const float* ln_g   = (const float*)d_in[2];
  const float* ln_b   = (const float*)d_in[3];
  const float* w_qkv  = (const float*)d_in[4];
  const float* w_av   = (const float*)d_in[5];
  const float* w_out  = (const float*)d_in[6];
  const float* b_out  = (const float*)d_in[7];
  const float* w_yout = (const float*)d_in[8];
  const float* b_yout = (const float*)d_in[9];
  float* out = (float*)d_out;

  _Float16* ws     = (_Float16*)d_ws;
  _Float16* xn     = ws;                 // 4096*1024
  _Float16* yh     = xn + 4194304;       // 4096*1024
  _Float16* wqkvT  = yh + 4194304;       // 3072*1024
  _Float16* wavT   = wqkvT + 3145728;    // 1024*1024
  _Float16* woutT  = wavT + 1048576;     // 1024*1024
  _Float16* wyoutT = woutT + 1048576;    // 1024*1024
  _Float16* qkvm   = wyoutT + 1048576;   // 4096*2048 (q|k)
  _Float16* vtb    = qkvm + 8388608;     // 32*64*2048
  _Float16* avtb   = vtb + 4194304;      // 32*64*2048
  _Float16* xc     = avtb + 4194304;     // 4096*1024
  _Float16* yc     = xc + 4194304;       // 4096*1024

  prep_kernel<<<9728, 256, 0, stream>>>(x, ln_g, ln_b, y, w_qkv, w_av, w_out, w_yout,
                                        xn, yh, wqkvT, wavT, woutT, wyoutT);

  gemm8p_kernel<<<256, 512, 0, stream>>>(xn, wqkvT, yh, wavT, qkvm, vtb, avtb);

  attn_kernel<<<512, 256, 0, stream>>>(qkvm, vtb, avtb, xc, yc);

  gemmout8p_kernel<<<128, 512, 0, stream>>>(
      xc, woutT, out, b_out,
      yc, wyoutT, out + 4194304, b_yout);
}

// Round 10
// 210.657 us; speedup vs baseline: 1.1490x; 1.1490x over previous
//
#include <hip/hip_runtime.h>

typedef _Float16 half8 __attribute__((ext_vector_type(8)));
typedef _Float16 half4v __attribute__((ext_vector_type(4)));
typedef float f32x4 __attribute__((ext_vector_type(4)));
typedef unsigned int u32;

#define SEQ 2048
#define NTOK 4096
#define DM 1024
#define QKS 2048
#define LN_EPS 1e-5f
#define LOG2E_SCALE 0.18033688f  // 0.125 * log2(e)

// ---------------- async global->LDS (16B per lane) ----------------
typedef const __attribute__((address_space(1))) u32* gas_ptr;
typedef __attribute__((address_space(3))) u32* las_ptr;
__device__ __forceinline__ void gld_lds16(const void* g, void* l) {
  __builtin_amdgcn_global_load_lds((gas_ptr)g, (las_ptr)l, 16, 0, 0);
}

#define BARRIER() do { __builtin_amdgcn_s_barrier(); __builtin_amdgcn_sched_barrier(0); } while (0)
#define VMW(N) do { asm volatile("s_waitcnt vmcnt(" #N ")" ::: "memory"); __builtin_amdgcn_sched_barrier(0); } while (0)
#define LGW() do { asm volatile("s_waitcnt lgkmcnt(0)" ::: "memory"); __builtin_amdgcn_sched_barrier(0); } while (0)

// ---------------- fused prepass: LN+cast, y cast, 4 weight transposes ----------------
__global__ __launch_bounds__(256) void prep_kernel(
    const float* __restrict__ x, const float* __restrict__ g, const float* __restrict__ bta,
    const float* __restrict__ y,
    const float* __restrict__ w_qkv, const float* __restrict__ w_av,
    const float* __restrict__ w_out, const float* __restrict__ w_yout,
    _Float16* __restrict__ xn, _Float16* __restrict__ yh,
    _Float16* __restrict__ wqkvT, _Float16* __restrict__ wavT,
    _Float16* __restrict__ woutT, _Float16* __restrict__ wyoutT) {
  __shared__ float smem[64 * 65];
  const int bid = blockIdx.x;
  const int t = threadIdx.x;
  if (bid < 4096) {  // LayerNorm row
    const int row = bid;
    const float4 v = ((const float4*)(x + (size_t)row * DM))[t];
    float s = v.x + v.y + v.z + v.w;
#pragma unroll
    for (int m = 1; m < 64; m <<= 1) s += __shfl_xor(s, m, 64);
    float* red = smem;
    const int wid = t >> 6, lane = t & 63;
    if (lane == 0) red[wid] = s;
    __syncthreads();
    const float mu = (red[0] + red[1] + red[2] + red[3]) * (1.0f / DM);
    const float dx = v.x - mu, dy = v.y - mu, dz = v.z - mu, dw = v.w - mu;
    float ss = dx * dx + dy * dy + dz * dz + dw * dw;
#pragma unroll
    for (int m = 1; m < 64; m <<= 1) ss += __shfl_xor(ss, m, 64);
    __syncthreads();
    if (lane == 0) red[wid] = ss;
    __syncthreads();
    const float var = (red[0] + red[1] + red[2] + red[3]) * (1.0f / DM);
    const float rstd = rsqrtf(var + LN_EPS);
    const float4 gg = ((const float4*)g)[t];
    const float4 bb = ((const float4*)bta)[t];
    half4v o;
    o[0] = (_Float16)(dx * rstd * gg.x + bb.x);
    o[1] = (_Float16)(dy * rstd * gg.y + bb.y);
    o[2] = (_Float16)(dz * rstd * gg.z + bb.z);
    o[3] = (_Float16)(dw * rstd * gg.w + bb.w);
    *(half4v*)(xn + (size_t)row * DM + t * 4) = o;
  } else if (bid < 8192) {  // y cast row
    const int row = bid - 4096;
    const float4 v = ((const float4*)(y + (size_t)row * DM))[t];
    half4v o;
    o[0] = (_Float16)v.x; o[1] = (_Float16)v.y;
    o[2] = (_Float16)v.z; o[3] = (_Float16)v.w;
    *(half4v*)(yh + (size_t)row * DM + t * 4) = o;
  } else {  // weight transpose+cast: W[K][Nc] -> WT[Nc][K]
    const int id2 = bid - 8192;
    const float* W; _Float16* WT; int Nc, bx, by;
    if (id2 < 768) { W = w_qkv; WT = wqkvT; Nc = 3072; bx = id2 % 48; by = id2 / 48; }
    else {
      const int id3 = id2 - 768, sel = id3 >> 8;
      Nc = 1024; bx = id3 & 15; by = (id3 >> 4) & 15;
      if (sel == 0) { W = w_av; WT = wavT; }
      else if (sel == 1) { W = w_out; WT = woutT; }
      else { W = w_yout; WT = wyoutT; }
    }
    float (*tile)[65] = (float(*)[65])smem;
    const int n0 = bx * 64, k0 = by * 64;
    const int c = t & 63;
#pragma unroll
    for (int i = 0; i < 16; i++) {
      const int r = (t >> 6) * 16 + i;
      tile[r][c] = W[(size_t)(k0 + r) * Nc + n0 + c];
    }
    __syncthreads();
#pragma unroll
    for (int i = 0; i < 16; i++) {
      const int n = (t >> 6) * 16 + i;
      WT[(size_t)(n0 + n) * 1024 + k0 + c] = (_Float16)tile[c][n];
    }
  }
}

// ---------------- 8-phase 256x256 GEMM (qkv + av fused), BK=32 dbuf ----------------
__global__ __launch_bounds__(512, 2) void gemm8p_kernel(
    const _Float16* __restrict__ xn, const _Float16* __restrict__ wqkvT,
    const _Float16* __restrict__ yh, const _Float16* __restrict__ wavT,
    _Float16* __restrict__ qkvm, _Float16* __restrict__ vtb,
    _Float16* __restrict__ avtb) {
  __shared__ _Float16 Ab[2][8192];
  __shared__ _Float16 Bb[2][8192];
  const int swz = ((blockIdx.x & 7) << 5) + (blockIdx.x >> 3);  // bijective, 256 blocks
  const _Float16 *A, *B;
  int m0, n0, isav;
  if (swz < 192) { A = xn; B = wqkvT; m0 = (swz / 12) * 256; n0 = (swz % 12) * 256; isav = 0; }
  else { const int u = swz - 192; A = yh; B = wavT; m0 = (u >> 2) * 256; n0 = (u & 3) * 256; isav = 1; }
  const int t = threadIdx.x;
  const int wid = t >> 6, lane = t & 63, lo = lane & 15, hi = lane >> 4;
  const int wm = wid >> 2, wn = wid & 3;
  const int srow = t >> 2;
  const int sx = ((t & 3) ^ (srow & 3)) << 3;  // swizzled 16B-chunk in source row
  const _Float16* gA = A + (size_t)(m0 + srow) * 1024 + sx;
  const _Float16* gB = B + (size_t)(n0 + srow) * 1024 + sx;
  const int rdz = (hi ^ (lo & 3)) << 3;
  const int arow = (wm * 128 + lo) * 32 + rdz;  // + f*512
  const int brow = (wn * 64 + lo) * 32 + rdz;   // + g*512

  f32x4 acc[8][4];
#pragma unroll
  for (int i = 0; i < 8; i++)
#pragma unroll
    for (int j = 0; j < 4; j++) {
      acc[i][j][0] = 0.f; acc[i][j][1] = 0.f; acc[i][j][2] = 0.f; acc[i][j][3] = 0.f;
    }
  half8 af[4], bf[4];

#define STG_A(BUF, HH, KT) gld_lds16(gA + (HH) * 131072 + (KT) * 32, &Ab[BUF][(HH) * 4096 + t * 8])
#define STG_B(BUF, HH, KT) gld_lds16(gB + (HH) * 131072 + (KT) * 32, &Bb[BUF][(HH) * 4096 + t * 8])
#define RDA(BUF, FB)                                                     \
  _Pragma("unroll") for (int f2 = 0; f2 < 4; f2++)                       \
      af[f2] = *(const half8*)&Ab[BUF][arow + ((FB) + f2) * 512]
#define RDB(BUF, G0)                                                     \
  _Pragma("unroll") for (int g2 = 0; g2 < 2; g2++)                       \
      bf[(G0) + g2] = *(const half8*)&Bb[BUF][brow + ((G0) + g2) * 512]
#define MMA(FB, G0)                                                      \
  do {                                                                   \
    __builtin_amdgcn_s_setprio(1);                                       \
    _Pragma("unroll") for (int f2 = 0; f2 < 4; f2++)                     \
        _Pragma("unroll") for (int g2 = 0; g2 < 2; g2++)                 \
            acc[(FB) + f2][(G0) + g2] = __builtin_amdgcn_mfma_f32_16x16x32_f16( \
                af[f2], bf[(G0) + g2], acc[(FB) + f2][(G0) + g2], 0, 0, 0); \
    __builtin_amdgcn_s_setprio(0);                                       \
  } while (0)

  // prologue: tile0 -> buf0 (4 halves), tile1 A-h0 -> buf1
  STG_A(0, 0, 0); STG_A(0, 1, 0); STG_B(0, 0, 0); STG_B(0, 1, 0);
  STG_A(1, 0, 1);

  for (int it = 0; it < 16; it++) {
    const int T1 = 2 * it + 1;
    const int N0 = (2 * it + 2) & 31, N1 = (2 * it + 3) & 31;
    // P0: open buf0
    VMW(1); BARRIER();
    RDA(0, 0); RDB(0, 0);
    STG_A(1, 1, T1);
    LGW(); MMA(0, 0);
    // P1
    BARRIER(); RDB(0, 2); STG_B(1, 0, T1); LGW(); MMA(0, 2);
    // P2
    BARRIER(); RDA(0, 4); STG_B(1, 1, T1); LGW(); MMA(4, 2);
    // P3
    BARRIER(); STG_A(0, 0, N0); MMA(4, 0);
    // P4: open buf1
    VMW(1); BARRIER();
    RDA(1, 0); RDB(1, 0);
    STG_A(0, 1, N0);
    LGW(); MMA(0, 0);
    // P5
    BARRIER(); RDB(1, 2); STG_B(0, 0, N0); LGW(); MMA(0, 2);
    // P6
    BARRIER(); RDA(1, 4); STG_B(0, 1, N0); LGW(); MMA(4, 2);
    // P7
    BARRIER(); STG_A(1, 0, N1); MMA(4, 0);
  }
#undef STG_A
#undef STG_B
#undef RDA
#undef RDB
#undef MMA

  // epilogue
#pragma unroll
  for (int f = 0; f < 8; f++)
#pragma unroll
    for (int g = 0; g < 4; g++)
#pragma unroll
      for (int r = 0; r < 4; r++) {
        const int row = m0 + wm * 128 + f * 16 + 4 * hi + r;
        const int col = n0 + wn * 64 + g * 16 + lo;
        const _Float16 v = (_Float16)acc[f][g][r];
        if (!isav && col < 2048) {
          qkvm[(size_t)row * QKS + col] = v;
        } else {
          const int coff = isav ? col : col - 2048;
          _Float16* Ct = isav ? avtb : vtb;
          Ct[(((size_t)((row >> 11) << 4) + (coff >> 6)) * 64 + (coff & 63)) * SEQ +
             (row & (SEQ - 1))] = v;
        }
      }
}

// ---------------- 8-phase 256x256 GEMM for output projections (f32 + bias) ----------------
__global__ __launch_bounds__(512, 2) void gemmout8p_kernel(
    const _Float16* __restrict__ xc, const _Float16* __restrict__ woutT,
    float* __restrict__ o0, const float* __restrict__ b0,
    const _Float16* __restrict__ yc, const _Float16* __restrict__ wyoutT,
    float* __restrict__ o1, const float* __restrict__ b1) {
  __shared__ _Float16 Ab[2][8192];
  __shared__ _Float16 Bb[2][8192];
  const int swz = ((blockIdx.x & 7) << 4) + (blockIdx.x >> 3);  // bijective, 128 blocks
  const _Float16 *A, *B;
  float* F; const float* bias;
  int u;
  if (swz < 64) { A = xc; B = woutT; F = o0; bias = b0; u = swz; }
  else { A = yc; B = wyoutT; F = o1; bias = b1; u = swz - 64; }
  const int m0 = (u >> 2) * 256, n0 = (u & 3) * 256;
  const int t = threadIdx.x;
  const int wid = t >> 6, lane = t & 63, lo = lane & 15, hi = lane >> 4;
  const int wm = wid >> 2, wn = wid & 3;
  const int srow = t >> 2;
  const int sx = ((t & 3) ^ (srow & 3)) << 3;
  const _Float16* gA = A + (size_t)(m0 + srow) * 1024 + sx;
  const _Float16* gB = B + (size_t)(n0 + srow) * 1024 + sx;
  const int rdz = (hi ^ (lo & 3)) << 3;
  const int arow = (wm * 128 + lo) * 32 + rdz;
  const int brow = (wn * 64 + lo) * 32 + rdz;

  f32x4 acc[8][4];
#pragma unroll
  for (int i = 0; i < 8; i++)
#pragma unroll
    for (int j = 0; j < 4; j++) {
      acc[i][j][0] = 0.f; acc[i][j][1] = 0.f; acc[i][j][2] = 0.f; acc[i][j][3] = 0.f;
    }
  half8 af[4], bf[4];

#define STG_A(BUF, HH, KT) gld_lds16(gA + (HH) * 131072 + (KT) * 32, &Ab[BUF][(HH) * 4096 + t * 8])
#define STG_B(BUF, HH, KT) gld_lds16(gB + (HH) * 131072 + (KT) * 32, &Bb[BUF][(HH) * 4096 + t * 8])
#define RDA(BUF, FB)                                                     \
  _Pragma("unroll") for (int f2 = 0; f2 < 4; f2++)                       \
      af[f2] = *(const half8*)&Ab[BUF][arow + ((FB) + f2) * 512]
#define RDB(BUF, G0)                                                     \
  _Pragma("unroll") for (int g2 = 0; g2 < 2; g2++)                       \
      bf[(G0) + g2] = *(const half8*)&Bb[BUF][brow + ((G0) + g2) * 512]
#define MMA(FB, G0)                                                      \
  do {                                                                   \
    __builtin_amdgcn_s_setprio(1);                                       \
    _Pragma("unroll") for (int f2 = 0; f2 < 4; f2++)                     \
        _Pragma("unroll") for (int g2 = 0; g2 < 2; g2++)                 \
            acc[(FB) + f2][(G0) + g2] = __builtin_amdgcn_mfma_f32_16x16x32_f16( \
                af[f2], bf[(G0) + g2], acc[(FB) + f2][(G0) + g2], 0, 0, 0); \
    __builtin_amdgcn_s_setprio(0);                                       \
  } while (0)

  STG_A(0, 0, 0); STG_A(0, 1, 0); STG_B(0, 0, 0); STG_B(0, 1, 0);
  STG_A(1, 0, 1);

  for (int it = 0; it < 16; it++) {
    const int T1 = 2 * it + 1;
    const int N0 = (2 * it + 2) & 31, N1 = (2 * it + 3) & 31;
    VMW(1); BARRIER();
    RDA(0, 0); RDB(0, 0);
    STG_A(1, 1, T1);
    LGW(); MMA(0, 0);
    BARRIER(); RDB(0, 2); STG_B(1, 0, T1); LGW(); MMA(0, 2);
    BARRIER(); RDA(0, 4); STG_B(1, 1, T1); LGW(); MMA(4, 2);
    BARRIER(); STG_A(0, 0, N0); MMA(4, 0);
    VMW(1); BARRIER();
    RDA(1, 0); RDB(1, 0);
    STG_A(0, 1, N0);
    LGW(); MMA(0, 0);
    BARRIER(); RDB(1, 2); STG_B(0, 0, N0); LGW(); MMA(0, 2);
    BARRIER(); RDA(1, 4); STG_B(0, 1, N0); LGW(); MMA(4, 2);
    BARRIER(); STG_A(1, 0, N1); MMA(4, 0);
  }
#undef STG_A
#undef STG_B
#undef RDA
#undef RDB
#undef MMA

#pragma unroll
  for (int f = 0; f < 8; f++)
#pragma unroll
    for (int g = 0; g < 4; g++)
#pragma unroll
      for (int r = 0; r < 4; r++) {
        const int row = m0 + wm * 128 + f * 16 + 4 * hi + r;
        const int col = n0 + wn * 64 + g * 16 + lo;
        F[(size_t)row * 1024 + col] = acc[f][g][r] + bias[col];
      }
}

// ---------------- flash attention v6: R3 schedule, TILE=32, QBLK=64, grid 1024 ----------------
// 4 waves x 16 q-rows; K/V/A all double-buffered (28KB LDS); one __syncthreads
// per tile, stage-early (R3-verified structure). 4 blocks/CU = 16 waves/CU.
__global__ __launch_bounds__(256, 4) void attn_kernel(
    const _Float16* __restrict__ qkvm,  // [NTOK][2048]: q | k
    const _Float16* __restrict__ vt,    // [32][64][SEQ]
    const _Float16* __restrict__ avt,   // [32][64][SEQ]
    _Float16* __restrict__ xctx, _Float16* __restrict__ yctx) {
  __shared__ _Float16 Kl[2][2048];   // [32 keys][64 d]
  __shared__ _Float16 Vl[2][2048];   // [64 d][32 keys]
  __shared__ _Float16 Al[2][2048];   // [64 d][32 keys]
  __shared__ _Float16 Pl[4][512];    // per-wave [16 q][32 keys]

  const int t = threadIdx.x;
  const int wid = t >> 6, lane = t & 63, lo = lane & 15, hi = lane >> 4;
  const int id = blockIdx.x;
  // XCD mapping: 128 consecutive-swz blocks per XCD -> 4 heads per XCD
  const int bh = ((id & 7) << 2) + ((id >> 3) >> 5);
  const int qt = (id >> 3) & 31;
  const int b = bh >> 4, h = bh & 15;
  const int q0 = qt * 64 + wid * 16;
  const size_t tokbase = (size_t)b * SEQ;
  const _Float16* vbase = vt + (size_t)bh * 64 * SEQ;
  const _Float16* abase = avt + (size_t)bh * 64 * SEQ;
  _Float16* Pw = Pl[wid];
  const int NT = SEQ / 32;
  const int swzP = (lo & 3) ^ ((lo >> 2) & 3);

  // Q as B-fragment: lane holds Q[q0+lo][kc*32 + hi*8 .. +7]
  half8 qf[2];
#pragma unroll
  for (int kc = 0; kc < 2; kc++)
    qf[kc] = *(const half8*)(qkvm + (tokbase + q0 + lo) * QKS +
                             h * 64 + kc * 32 + hi * 8);

  f32x4 zero;
  zero[0] = 0.f; zero[1] = 0.f; zero[2] = 0.f; zero[3] = 0.f;
  f32x4 accx[4], accy[4];
  float mC = -1.0e30f, lsum = 0.0f;  // per-lane state for query q0+lo
#pragma unroll
  for (int j = 0; j < 4; j++) { accx[j] = zero; accy[j] = zero; }

  // staging geometry
  const int kkey = t >> 3, kc7 = t & 7;                 // K: key row, chunk
  const int vrow = t >> 2, vc3 = t & 3;                 // V/A: d row, chunk
  const int kcs = ((kc7 ^ (kkey & 7)) << 3);
  const int vcs = ((vc3 ^ ((vrow & 3) ^ ((vrow >> 2) & 3))) << 3);

#define STAGE(kv0, BSEL)                                                          \
  do {                                                                            \
    gld_lds16(qkvm + (tokbase + (kv0) + kkey) * QKS + DM + h * 64 + kcs,          \
              &Kl[BSEL][(t >> 6) * 512 + (t & 63) * 8]);                          \
    gld_lds16(vbase + (size_t)vrow * SEQ + (kv0) + vcs,                           \
              &Vl[BSEL][(t >> 6) * 512 + (t & 63) * 8]);                          \
    gld_lds16(abase + (size_t)vrow * SEQ + (kv0) + vcs,                           \
              &Al[BSEL][(t >> 6) * 512 + (t & 63) * 8]);                          \
  } while (0)

  STAGE(0, 0);
  int bsel = 0;
  for (int tt = 0; tt < NT; tt++) {
    __syncthreads();  // stage(tt) complete (each wave drains vmcnt at barrier)
    if (tt + 1 < NT) STAGE((tt + 1) * 32, bsel ^ 1);
    const _Float16* Kb = Kl[bsel];
    const _Float16* Vb = Vl[bsel];
    const _Float16* Ab = Al[bsel];

    // ---- S^T = K Q^T : s[kg], row(key)=kg*16+4*hi+r, col(query)=lo ----
    f32x4 s[2];
#pragma unroll
    for (int kg = 0; kg < 2; kg++) {
      const int krow = kg * 16 + lo;
      const int kr = krow * 64;
      const half8 ak0 = *(const half8*)(Kb + kr + ((hi ^ (krow & 7)) << 3));
      const half8 ak1 = *(const half8*)(Kb + kr + (((4 | hi) ^ (krow & 7)) << 3));
      f32x4 z = __builtin_amdgcn_mfma_f32_16x16x32_f16(ak0, qf[0], zero, 0, 0, 0);
      s[kg] = __builtin_amdgcn_mfma_f32_16x16x32_f16(ak1, qf[1], z, 0, 0, 0);
    }

    // ---- in-lane tile max (8) + 2-step cross-lane ----
    float tm = -3.0e38f;
#pragma unroll
    for (int kg = 0; kg < 2; kg++)
#pragma unroll
      for (int r = 0; r < 4; r++) tm = fmaxf(tm, s[kg][r]);
    tm = fmaxf(tm, __shfl_xor(tm, 16, 64));
    tm = fmaxf(tm, __shfl_xor(tm, 32, 64));
    const float tmC = tm * LOG2E_SCALE;

    // ---- defer-max rescale ----
    if (__any(tmC > mC + 8.0f)) {
      const float mn = fmaxf(mC, tmC);
      const float fcs = exp2f(mC - mn);
      mC = mn;
      lsum *= fcs;
#pragma unroll
      for (int r = 0; r < 4; r++) {
        const float fcb = __shfl(fcs, 4 * hi + r, 64);
#pragma unroll
        for (int ng = 0; ng < 4; ng++) {
          accx[ng][r] *= fcb;
          accy[ng][r] *= fcb;
        }
      }
    }

    // ---- P = exp2(s*C - mC), in-lane sum, packed b64 write ----
    {
      float rs = 0.0f;
#pragma unroll
      for (int kg = 0; kg < 2; kg++) {
        half4v pk;
#pragma unroll
        for (int r = 0; r < 4; r++) {
          const float p = exp2f(fmaf(s[kg][r], LOG2E_SCALE, -mC));
          rs += p;
          pk[r] = (_Float16)p;
        }
        *(half4v*)(Pw + lo * 32 +
                   (((kg * 2 + (hi >> 1)) ^ swzP) << 3) + ((hi & 1) << 2)) = pk;
      }
      rs += __shfl_xor(rs, 16, 64);
      rs += __shfl_xor(rs, 32, 64);
      lsum += rs;
    }

    // ---- PV for both value streams (single K=32 step) ----
    {
      const half8 pa = *(const half8*)(Pw + lo * 32 + ((hi ^ swzP) << 3));
#pragma unroll
      for (int ng = 0; ng < 4; ng++) {
        const int vrow2 = ng * 16 + lo;
        const int vr = vrow2 * 32 + ((hi ^ ((vrow2 & 3) ^ ((vrow2 >> 2) & 3))) << 3);
        const half8 bv = *(const half8*)(Vb + vr);
        const half8 ba = *(const half8*)(Ab + vr);
        accx[ng] = __builtin_amdgcn_mfma_f32_16x16x32_f16(pa, bv, accx[ng], 0, 0, 0);
        accy[ng] = __builtin_amdgcn_mfma_f32_16x16x32_f16(pa, ba, accy[ng], 0, 0, 0);
      }
    }
    bsel ^= 1;
  }
#undef STAGE

  // ---- normalize and store ----
  const float inv = 1.0f / lsum;
#pragma unroll
  for (int r = 0; r < 4; r++) {
    const float invb = __shfl(inv, 4 * hi + r, 64);
    const size_t tok = tokbase + q0 + 4 * hi + r;
#pragma unroll
    for (int ng = 0; ng < 4; ng++) {
      const int col = h * 64 + ng * 16 + lo;
      xctx[tok * DM + col] = (_Float16)(accx[ng][r] * invb);
      yctx[tok * DM + col] = (_Float16)(accy[ng][r] * invb);
    }
  }
}

// ---------------- launch ----------------
extern "C" void kernel_launch(void* const* d_in, const int* in_sizes, int n_in,
                              void* d_out, int out_size, void* d_ws, size_t ws_size,
                              hipStream_t stream) {
  const float* x      = (const float*)d_in[0];
  const float* y      = (const float*)d_in[1];
  const float* ln_g   = (const float*)d_in[2];
  const float* ln_b   = (const float*)d_in[3];
  const float* w_qkv  = (const float*)d_in[4];
  const float* w_av   = (const float*)d_in[5];
  const float* w_out  = (const float*)d_in[6];
  const float* b_out  = (const float*)d_in[7];
  const float* w_yout = (const float*)d_in[8];
  const float* b_yout = (const float*)d_in[9];
  float* out = (float*)d_out;

  _Float16* ws     = (_Float16*)d_ws;
  _Float16* xn     = ws;                 // 4096*1024
  _Float16* yh     = xn + 4194304;       // 4096*1024
  _Float16* wqkvT  = yh + 4194304;       // 3072*1024
  _Float16* wavT   = wqkvT + 3145728;    // 1024*1024
  _Float16* woutT  = wavT + 1048576;     // 1024*1024
  _Float16* wyoutT = woutT + 1048576;    // 1024*1024
  _Float16* qkvm   = wyoutT + 1048576;   // 4096*2048 (q|k)
  _Float16* vtb    = qkvm + 8388608;     // 32*64*2048
  _Float16* avtb   = vtb + 4194304;      // 32*64*2048
  _Float16* xc     = avtb + 4194304;     // 4096*1024
  _Float16* yc     = xc + 4194304;       // 4096*1024

  prep_kernel<<<9728, 256, 0, stream>>>(x, ln_g, ln_b, y, w_qkv, w_av, w_out, w_yout,
                                        xn, yh, wqkvT, wavT, woutT, wyoutT);

  gemm8p_kernel<<<256, 512, 0, stream>>>(xn, wqkvT, yh, wavT, qkvm, vtb, avtb);

  attn_kernel<<<1024, 256, 0, stream>>>(qkvm, vtb, avtb, xc, yc);

  gemmout8p_kernel<<<128, 512, 0, stream>>>(
      xc, woutT, out, b_out,
      yc, wyoutT, out + 4194304, b_yout);
}

// Round 11
// 200.197 us; speedup vs baseline: 1.2091x; 1.0522x over previous
//
#include <hip/hip_runtime.h>

typedef _Float16 half8 __attribute__((ext_vector_type(8)));
typedef _Float16 half4v __attribute__((ext_vector_type(4)));
typedef float f32x4 __attribute__((ext_vector_type(4)));
typedef unsigned int u32;

#define SEQ 2048
#define NTOK 4096
#define DM 1024
#define QKS 2048
#define LN_EPS 1e-5f
#define LOG2E_SCALE 0.18033688f  // 0.125 * log2(e)

// ---------------- async global->LDS (16B per lane) ----------------
typedef const __attribute__((address_space(1))) u32* gas_ptr;
typedef __attribute__((address_space(3))) u32* las_ptr;
__device__ __forceinline__ void gld_lds16(const void* g, void* l) {
  __builtin_amdgcn_global_load_lds((gas_ptr)g, (las_ptr)l, 16, 0, 0);
}

#define BARRIER() do { __builtin_amdgcn_s_barrier(); __builtin_amdgcn_sched_barrier(0); } while (0)
#define VMW(N) do { asm volatile("s_waitcnt vmcnt(" #N ")" ::: "memory"); __builtin_amdgcn_sched_barrier(0); } while (0)
#define LGW() do { asm volatile("s_waitcnt lgkmcnt(0)" ::: "memory"); __builtin_amdgcn_sched_barrier(0); } while (0)

// ---------------- fused prepass: LN+cast, y cast, 4 weight transposes ----------------
__global__ __launch_bounds__(256) void prep_kernel(
    const float* __restrict__ x, const float* __restrict__ g, const float* __restrict__ bta,
    const float* __restrict__ y,
    const float* __restrict__ w_qkv, const float* __restrict__ w_av,
    const float* __restrict__ w_out, const float* __restrict__ w_yout,
    _Float16* __restrict__ xn, _Float16* __restrict__ yh,
    _Float16* __restrict__ wqkvT, _Float16* __restrict__ wavT,
    _Float16* __restrict__ woutT, _Float16* __restrict__ wyoutT) {
  __shared__ float smem[64 * 65];
  const int bid = blockIdx.x;
  const int t = threadIdx.x;
  if (bid < 4096) {  // LayerNorm row
    const int row = bid;
    const float4 v = ((const float4*)(x + (size_t)row * DM))[t];
    float s = v.x + v.y + v.z + v.w;
#pragma unroll
    for (int m = 1; m < 64; m <<= 1) s += __shfl_xor(s, m, 64);
    float* red = smem;
    const int wid = t >> 6, lane = t & 63;
    if (lane == 0) red[wid] = s;
    __syncthreads();
    const float mu = (red[0] + red[1] + red[2] + red[3]) * (1.0f / DM);
    const float dx = v.x - mu, dy = v.y - mu, dz = v.z - mu, dw = v.w - mu;
    float ss = dx * dx + dy * dy + dz * dz + dw * dw;
#pragma unroll
    for (int m = 1; m < 64; m <<= 1) ss += __shfl_xor(ss, m, 64);
    __syncthreads();
    if (lane == 0) red[wid] = ss;
    __syncthreads();
    const float var = (red[0] + red[1] + red[2] + red[3]) * (1.0f / DM);
    const float rstd = rsqrtf(var + LN_EPS);
    const float4 gg = ((const float4*)g)[t];
    const float4 bb = ((const float4*)bta)[t];
    half4v o;
    o[0] = (_Float16)(dx * rstd * gg.x + bb.x);
    o[1] = (_Float16)(dy * rstd * gg.y + bb.y);
    o[2] = (_Float16)(dz * rstd * gg.z + bb.z);
    o[3] = (_Float16)(dw * rstd * gg.w + bb.w);
    *(half4v*)(xn + (size_t)row * DM + t * 4) = o;
  } else if (bid < 8192) {  // y cast row
    const int row = bid - 4096;
    const float4 v = ((const float4*)(y + (size_t)row * DM))[t];
    half4v o;
    o[0] = (_Float16)v.x; o[1] = (_Float16)v.y;
    o[2] = (_Float16)v.z; o[3] = (_Float16)v.w;
    *(half4v*)(yh + (size_t)row * DM + t * 4) = o;
  } else {  // weight transpose+cast: W[K][Nc] -> WT[Nc][K]
    const int id2 = bid - 8192;
    const float* W; _Float16* WT; int Nc, bx, by;
    if (id2 < 768) { W = w_qkv; WT = wqkvT; Nc = 3072; bx = id2 % 48; by = id2 / 48; }
    else {
      const int id3 = id2 - 768, sel = id3 >> 8;
      Nc = 1024; bx = id3 & 15; by = (id3 >> 4) & 15;
      if (sel == 0) { W = w_av; WT = wavT; }
      else if (sel == 1) { W = w_out; WT = woutT; }
      else { W = w_yout; WT = wyoutT; }
    }
    float (*tile)[65] = (float(*)[65])smem;
    const int n0 = bx * 64, k0 = by * 64;
    const int c = t & 63;
#pragma unroll
    for (int i = 0; i < 16; i++) {
      const int r = (t >> 6) * 16 + i;
      tile[r][c] = W[(size_t)(k0 + r) * Nc + n0 + c];
    }
    __syncthreads();
#pragma unroll
    for (int i = 0; i < 16; i++) {
      const int n = (t >> 6) * 16 + i;
      WT[(size_t)(n0 + n) * 1024 + k0 + c] = (_Float16)tile[c][n];
    }
  }
}

// ---------------- m201-style 8-phase 256x256 GEMM, BK=64, 128KB LDS (qkv + av) ----------------
// 512 thr = 8 waves (2Mx4N); per-wave 128x64; 16 MFMA/phase; VMW(2) at P0/P4 only.
__global__ __launch_bounds__(512, 1) void gemm8p_kernel(
    const _Float16* __restrict__ xn, const _Float16* __restrict__ wqkvT,
    const _Float16* __restrict__ yh, const _Float16* __restrict__ wavT,
    _Float16* __restrict__ qkvm, _Float16* __restrict__ vtb,
    _Float16* __restrict__ avtb) {
  __shared__ _Float16 Ab[2][16384];   // [256 rows][64 k], chunk^=(row&7)
  __shared__ _Float16 Bb[2][16384];
  const int swz = ((blockIdx.x & 7) << 5) + (blockIdx.x >> 3);  // bijective, 256 blocks
  const _Float16 *A, *B;
  int m0, n0, isav;
  if (swz < 192) { A = xn; B = wqkvT; m0 = (swz / 12) * 256; n0 = (swz % 12) * 256; isav = 0; }
  else { const int u = swz - 192; A = yh; B = wavT; m0 = (u >> 2) * 256; n0 = (u & 3) * 256; isav = 1; }
  const int t = threadIdx.x;
  const int wid = t >> 6, lane = t & 63, lo = lane & 15, hi = lane >> 4;
  const int wm = wid >> 2, wn = wid & 3;
  // staging: thread t covers row p*64 + (t>>3), chunk t&7 (of 8 per 128B row)
  const int srow = t >> 3;
  const int schk = t & 7;
  const _Float16* gA = A + (size_t)(m0 + srow) * 1024 + ((schk ^ (srow & 7)) << 3);
  const _Float16* gB = B + (size_t)(n0 + srow) * 1024 + ((schk ^ (srow & 7)) << 3);
  // fragment read bases: row = (wm*128|wn*64) + f*16 + lo; octet o at chunk o^(row&7)
  const int arow = (wm * 128 + lo) * 64;
  const int brow = (wn * 64 + lo) * 64;
  const int rz0 = ((hi ^ (lo & 7)) << 3);
  const int rz1 = (((4 | hi) ^ (lo & 7)) << 3);

  f32x4 acc[8][4];
#pragma unroll
  for (int i = 0; i < 8; i++)
#pragma unroll
    for (int j = 0; j < 4; j++) {
      acc[i][j][0] = 0.f; acc[i][j][1] = 0.f; acc[i][j][2] = 0.f; acc[i][j][3] = 0.f;
    }
  half8 af[4][2], bf[4][2];

#define STG_A(BUF, P, KT) gld_lds16(gA + (P) * 65536 + (KT) * 64, &Ab[BUF][(P) * 4096 + t * 8])
#define STG_B(BUF, P, KT) gld_lds16(gB + (P) * 65536 + (KT) * 64, &Bb[BUF][(P) * 4096 + t * 8])
#define RDA8(BUF, FB)                                                       \
  _Pragma("unroll") for (int f2 = 0; f2 < 4; f2++) {                        \
    af[f2][0] = *(const half8*)&Ab[BUF][arow + ((FB) + f2) * 1024 + rz0];   \
    af[f2][1] = *(const half8*)&Ab[BUF][arow + ((FB) + f2) * 1024 + rz1];   \
  }
#define RDB4(BUF, G0)                                                       \
  _Pragma("unroll") for (int g2 = 0; g2 < 2; g2++) {                        \
    bf[(G0) + g2][0] = *(const half8*)&Bb[BUF][brow + ((G0) + g2) * 1024 + rz0]; \
    bf[(G0) + g2][1] = *(const half8*)&Bb[BUF][brow + ((G0) + g2) * 1024 + rz1]; \
  }
#define MMA16(FB, G0)                                                       \
  do {                                                                      \
    __builtin_amdgcn_s_setprio(1);                                          \
    _Pragma("unroll") for (int f2 = 0; f2 < 4; f2++)                        \
      _Pragma("unroll") for (int g2 = 0; g2 < 2; g2++)                      \
        _Pragma("unroll") for (int ks = 0; ks < 2; ks++)                    \
          acc[(FB) + f2][(G0) + g2] = __builtin_amdgcn_mfma_f32_16x16x32_f16( \
              af[f2][ks], bf[(G0) + g2][ks], acc[(FB) + f2][(G0) + g2], 0, 0, 0); \
    __builtin_amdgcn_s_setprio(0);                                          \
  } while (0)

  // prologue: buf0 <- tile0 (8 glds), buf1 <- tile1 A passes 0,1
  STG_A(0, 0, 0); STG_A(0, 1, 0); STG_A(0, 2, 0); STG_A(0, 3, 0);
  STG_B(0, 0, 0); STG_B(0, 1, 0); STG_B(0, 2, 0); STG_B(0, 3, 0);
  STG_A(1, 0, 1); STG_A(1, 1, 1);

  for (int it = 0; it < 8; it++) {
    const int T1 = 2 * it + 1;
    const int N0 = (2 * it + 2) & 15, N1 = (2 * it + 3) & 15;
    // P0: open buf0 (retire its 8; keep buf1's 2 in flight)
    VMW(2); BARRIER();
    RDA8(0, 0); RDB4(0, 0);
    STG_A(1, 2, T1); STG_A(1, 3, T1);
    LGW(); MMA16(0, 0);
    // P1
    BARRIER(); RDB4(0, 2); STG_B(1, 0, T1); STG_B(1, 1, T1); LGW(); MMA16(0, 2);
    // P2
    BARRIER(); RDA8(0, 4); STG_B(1, 2, T1); STG_B(1, 3, T1); LGW(); MMA16(4, 2);
    // P3 (buf0 fully consumed -> start restaging)
    BARRIER(); STG_A(0, 0, N0); STG_A(0, 1, N0); MMA16(4, 0);
    // P4: open buf1
    VMW(2); BARRIER();
    RDA8(1, 0); RDB4(1, 0);
    STG_A(0, 2, N0); STG_A(0, 3, N0);
    LGW(); MMA16(0, 0);
    // P5
    BARRIER(); RDB4(1, 2); STG_B(0, 0, N0); STG_B(0, 1, N0); LGW(); MMA16(0, 2);
    // P6
    BARRIER(); RDA8(1, 4); STG_B(0, 2, N0); STG_B(0, 3, N0); LGW(); MMA16(4, 2);
    // P7
    BARRIER(); STG_A(1, 0, N1); STG_A(1, 1, N1); MMA16(4, 0);
  }
#undef STG_A
#undef STG_B
#undef RDA8
#undef RDB4
#undef MMA16

  // epilogue
#pragma unroll
  for (int f = 0; f < 8; f++)
#pragma unroll
    for (int g = 0; g < 4; g++)
#pragma unroll
      for (int r = 0; r < 4; r++) {
        const int row = m0 + wm * 128 + f * 16 + 4 * hi + r;
        const int col = n0 + wn * 64 + g * 16 + lo;
        const _Float16 v = (_Float16)acc[f][g][r];
        if (!isav && col < 2048) {
          qkvm[(size_t)row * QKS + col] = v;
        } else {
          const int coff = isav ? col : col - 2048;
          _Float16* Ct = isav ? avtb : vtb;
          Ct[(((size_t)((row >> 11) << 4) + (coff >> 6)) * 64 + (coff & 63)) * SEQ +
             (row & (SEQ - 1))] = v;
        }
      }
}

// ---------------- output-projection GEMM: 128x128, f32 + bias (512 blocks) ----------------
__global__ __launch_bounds__(256) void gemmout_kernel(
    const _Float16* __restrict__ A0, const _Float16* __restrict__ B0,
    float* F0, const float* bias0, int nblk0,
    const _Float16* __restrict__ A1, const _Float16* __restrict__ B1,
    float* F1, const float* bias1) {
  __shared__ _Float16 As[128 * 32];
  __shared__ _Float16 Bs[128 * 32];
  int id = ((blockIdx.x & 7) * (gridDim.x >> 3)) + (blockIdx.x >> 3);
  const _Float16 *A, *BT;
  float* Cf; const float* bias;
  if (id < nblk0) { A = A0; BT = B0; Cf = F0; bias = bias0; }
  else { id -= nblk0; A = A1; BT = B1; Cf = F1; bias = bias1; }
  const int bx = id & 7, by = id >> 3;
  const int t = threadIdx.x;
  const int wid = t >> 6, lane = t & 63, lo = lane & 15, hi = lane >> 4;
  const int wm = wid >> 1, wn = wid & 1;
  const int m0 = by * 128, n0 = bx * 128;
  const int K = 1024;

  f32x4 acc[4][4];
#pragma unroll
  for (int i = 0; i < 4; i++)
#pragma unroll
    for (int j = 0; j < 4; j++) {
      acc[i][j][0] = 0.f; acc[i][j][1] = 0.f; acc[i][j][2] = 0.f; acc[i][j][3] = 0.f;
    }
  const int rowA = t >> 2;
  const int kcol = (t & 3) * 8;
  const _Float16* gA = A + (size_t)(m0 + rowA) * K + kcol;
  const _Float16* gB = BT + (size_t)(n0 + rowA) * K + kcol;

  for (int k0 = 0; k0 < K; k0 += 32) {
#pragma unroll
    for (int j = 0; j < 2; j++) {
      gld_lds16(gA + (size_t)(j * 64) * K + k0, As + j * 2048 + wid * 512);
      gld_lds16(gB + (size_t)(j * 64) * K + k0, Bs + j * 2048 + wid * 512);
    }
    __syncthreads();
    half8 af[4], bf[4];
#pragma unroll
    for (int i = 0; i < 4; i++) {
      af[i] = *(const half8*)(As + (wm * 64 + i * 16 + lo) * 32 + hi * 8);
      bf[i] = *(const half8*)(Bs + (wn * 64 + i * 16 + lo) * 32 + hi * 8);
    }
#pragma unroll
    for (int i = 0; i < 4; i++)
#pragma unroll
      for (int j = 0; j < 4; j++)
        acc[i][j] = __builtin_amdgcn_mfma_f32_16x16x32_f16(af[i], bf[j], acc[i][j], 0, 0, 0);
    __syncthreads();
  }
#pragma unroll
  for (int i = 0; i < 4; i++)
#pragma unroll
    for (int j = 0; j < 4; j++)
#pragma unroll
      for (int r = 0; r < 4; r++) {
        const int row = m0 + wm * 64 + i * 16 + 4 * hi + r;
        const int col = n0 + wn * 64 + j * 16 + lo;
        Cf[(size_t)row * 1024 + col] = acc[i][j][r] + bias[col];
      }
}

// ---------------- flash attention v8: TILE=32, QBLK=64, shuffle-free steady loop ----------------
// 4 waves x 16 q-rows; K/V/A dbuf (28KB); in-lane defer-max trigger; lsum reduce hoisted.
__global__ __launch_bounds__(256, 4) void attn_kernel(
    const _Float16* __restrict__ qkvm,  // [NTOK][2048]: q | k
    const _Float16* __restrict__ vt,    // [32][64][SEQ]
    const _Float16* __restrict__ avt,   // [32][64][SEQ]
    _Float16* __restrict__ xctx, _Float16* __restrict__ yctx) {
  __shared__ _Float16 Kl[2][2048];   // [32 keys][64 d]
  __shared__ _Float16 Vl[2][2048];   // [64 d][32 keys]
  __shared__ _Float16 Al[2][2048];   // [64 d][32 keys]
  __shared__ _Float16 Pl[4][512];    // per-wave [16 q][32 keys]

  const int t = threadIdx.x;
  const int wid = t >> 6, lane = t & 63, lo = lane & 15, hi = lane >> 4;
  const int id = blockIdx.x;
  const int bh = ((id & 7) << 2) + ((id >> 3) >> 5);
  const int qt = (id >> 3) & 31;
  const int b = bh >> 4, h = bh & 15;
  const int q0 = qt * 64 + wid * 16;
  const size_t tokbase = (size_t)b * SEQ;
  const _Float16* vbase = vt + (size_t)bh * 64 * SEQ;
  const _Float16* abase = avt + (size_t)bh * 64 * SEQ;
  _Float16* Pw = Pl[wid];
  const int NT = SEQ / 32;
  const int swzP = (lo & 3) ^ ((lo >> 2) & 3);

  // Q as B-fragment: lane holds Q[q0+lo][kc*32 + hi*8 .. +7]
  half8 qf[2];
#pragma unroll
  for (int kc = 0; kc < 2; kc++)
    qf[kc] = *(const half8*)(qkvm + (tokbase + q0 + lo) * QKS +
                             h * 64 + kc * 32 + hi * 8);

  f32x4 zero;
  zero[0] = 0.f; zero[1] = 0.f; zero[2] = 0.f; zero[3] = 0.f;
  f32x4 accx[4], accy[4];
  float mC = -1.0e30f, lsum = 0.0f;  // per-lane; lsum is a per-lane PARTIAL
#pragma unroll
  for (int j = 0; j < 4; j++) { accx[j] = zero; accy[j] = zero; }

  // staging geometry
  const int kkey = t >> 3, kc7 = t & 7;
  const int vrow = t >> 2, vc3 = t & 3;
  const int kcs = ((kc7 ^ (kkey & 7)) << 3);
  const int vcs = ((vc3 ^ ((vrow & 3) ^ ((vrow >> 2) & 3))) << 3);

#define STAGE(kv0, BSEL)                                                          \
  do {                                                                            \
    gld_lds16(qkvm + (tokbase + (kv0) + kkey) * QKS + DM + h * 64 + kcs,          \
              &Kl[BSEL][(t >> 6) * 512 + (t & 63) * 8]);                          \
    gld_lds16(vbase + (size_t)vrow * SEQ + (kv0) + vcs,                           \
              &Vl[BSEL][(t >> 6) * 512 + (t & 63) * 8]);                          \
    gld_lds16(abase + (size_t)vrow * SEQ + (kv0) + vcs,                           \
              &Al[BSEL][(t >> 6) * 512 + (t & 63) * 8]);                          \
  } while (0)

  STAGE(0, 0);
  int bsel = 0;
  for (int tt = 0; tt < NT; tt++) {
    __syncthreads();
    if (tt + 1 < NT) STAGE((tt + 1) * 32, bsel ^ 1);
    const _Float16* Kb = Kl[bsel];
    const _Float16* Vb = Vl[bsel];
    const _Float16* Ab = Al[bsel];

    // ---- S^T = K Q^T : s[kg], row(key)=kg*16+4*hi+r, col(query)=lo ----
    f32x4 s[2];
#pragma unroll
    for (int kg = 0; kg < 2; kg++) {
      const int krow = kg * 16 + lo;
      const int kr = krow * 64;
      const half8 ak0 = *(const half8*)(Kb + kr + ((hi ^ (krow & 7)) << 3));
      const half8 ak1 = *(const half8*)(Kb + kr + (((4 | hi) ^ (krow & 7)) << 3));
      f32x4 z = __builtin_amdgcn_mfma_f32_16x16x32_f16(ak0, qf[0], zero, 0, 0, 0);
      s[kg] = __builtin_amdgcn_mfma_f32_16x16x32_f16(ak1, qf[1], z, 0, 0, 0);
    }

    // ---- in-lane max; cross-lane work only when growth detected ----
    float tm = -3.0e38f;
#pragma unroll
    for (int kg = 0; kg < 2; kg++)
#pragma unroll
      for (int r = 0; r < 4; r++) tm = fmaxf(tm, s[kg][r]);
    if (__any(tm * LOG2E_SCALE > mC + 8.0f)) {
      float tw = tm;
      tw = fmaxf(tw, __shfl_xor(tw, 16, 64));
      tw = fmaxf(tw, __shfl_xor(tw, 32, 64));
      const float mn = fmaxf(mC, tw * LOG2E_SCALE);
      const float fcs = exp2f(mC - mn);
      mC = mn;
      lsum *= fcs;
#pragma unroll
      for (int r = 0; r < 4; r++) {
        const float fcb = __shfl(fcs, 4 * hi + r, 64);
#pragma unroll
        for (int ng = 0; ng < 4; ng++) {
          accx[ng][r] *= fcb;
          accy[ng][r] *= fcb;
        }
      }
    }

    // ---- P = exp2(s*C - mC), per-lane partial sum, packed b64 write ----
    {
      float rs = 0.0f;
#pragma unroll
      for (int kg = 0; kg < 2; kg++) {
        half4v pk;
#pragma unroll
        for (int r = 0; r < 4; r++) {
          const float p = exp2f(fmaf(s[kg][r], LOG2E_SCALE, -mC));
          rs += p;
          pk[r] = (_Float16)p;
        }
        *(half4v*)(Pw + lo * 32 +
                   (((kg * 2 + (hi >> 1)) ^ swzP) << 3) + ((hi & 1) << 2)) = pk;
      }
      lsum += rs;  // cross-lane reduce deferred to epilogue
    }

    // ---- PV for both value streams ----
    {
      const half8 pa = *(const half8*)(Pw + lo * 32 + ((hi ^ swzP) << 3));
#pragma unroll
      for (int ng = 0; ng < 4; ng++) {
        const int vrow2 = ng * 16 + lo;
        const int vr = vrow2 * 32 + ((hi ^ ((vrow2 & 3) ^ ((vrow2 >> 2) & 3))) << 3);
        const half8 bv = *(const half8*)(Vb + vr);
        const half8 ba = *(const half8*)(Ab + vr);
        accx[ng] = __builtin_amdgcn_mfma_f32_16x16x32_f16(pa, bv, accx[ng], 0, 0, 0);
        accy[ng] = __builtin_amdgcn_mfma_f32_16x16x32_f16(pa, ba, accy[ng], 0, 0, 0);
      }
    }
    bsel ^= 1;
  }
#undef STAGE

  // ---- final cross-lane lsum reduce, normalize, store ----
  lsum += __shfl_xor(lsum, 16, 64);
  lsum += __shfl_xor(lsum, 32, 64);
  const float inv = 1.0f / lsum;
#pragma unroll
  for (int r = 0; r < 4; r++) {
    const float invb = __shfl(inv, 4 * hi + r, 64);
    const size_t tok = tokbase + q0 + 4 * hi + r;
#pragma unroll
    for (int ng = 0; ng < 4; ng++) {
      const int col = h * 64 + ng * 16 + lo;
      xctx[tok * DM + col] = (_Float16)(accx[ng][r] * invb);
      yctx[tok * DM + col] = (_Float16)(accy[ng][r] * invb);
    }
  }
}

// ---------------- launch ----------------
extern "C" void kernel_launch(void* const* d_in, const int* in_sizes, int n_in,
                              void* d_out, int out_size, void* d_ws, size_t ws_size,
                              hipStream_t stream) {
  const float* x      = (const float*)d_in[0];
  const float* y      = (const float*)d_in[1];
  const float* ln_g   = (const float*)d_in[2];
  const float* ln_b   = (const float*)d_in[3];
  const float* w_qkv  = (const float*)d_in[4];
  const float* w_av   = (const float*)d_in[5];
  const float* w_out  = (const float*)d_in[6];
  const float* b_out  = (const float*)d_in[7];
  const float* w_yout = (const float*)d_in[8];
  const float* b_yout = (const float*)d_in[9];
  float* out = (float*)d_out;

  _Float16* ws     = (_Float16*)d_ws;
  _Float16* xn     = ws;                 // 4096*1024
  _Float16* yh     = xn + 4194304;       // 4096*1024
  _Float16* wqkvT  = yh + 4194304;       // 3072*1024
  _Float16* wavT   = wqkvT + 3145728;    // 1024*1024
  _Float16* woutT  = wavT + 1048576;     // 1024*1024
  _Float16* wyoutT = woutT + 1048576;    // 1024*1024
  _Float16* qkvm   = wyoutT + 1048576;   // 4096*2048 (q|k)
  _Float16* vtb    = qkvm + 8388608;     // 32*64*2048
  _Float16* avtb   = vtb + 4194304;      // 32*64*2048
  _Float16* xc     = avtb + 4194304;     // 4096*1024
  _Float16* yc     = xc + 4194304;       // 4096*1024

  prep_kernel<<<9728, 256, 0, stream>>>(x, ln_g, ln_b, y, w_qkv, w_av, w_out, w_yout,
                                        xn, yh, wqkvT, wavT, woutT, wyoutT);

  gemm8p_kernel<<<256, 512, 0, stream>>>(xn, wqkvT, yh, wavT, qkvm, vtb, avtb);

  attn_kernel<<<1024, 256, 0, stream>>>(qkvm, vtb, avtb, xc, yc);

  gemmout_kernel<<<512, 256, 0, stream>>>(
      xc, woutT, out, b_out, 256,
      yc, wyoutT, out + 4194304, b_yout);
}